// Round 7
// baseline (454.355 us; speedup 1.0000x reference)
//
#include <hip/hip_runtime.h>

typedef short s8v __attribute__((ext_vector_type(8)));
typedef float f4v __attribute__((ext_vector_type(4)));

#define MFMA16(a,b,c) __builtin_amdgcn_mfma_f32_16x16x32_bf16(a,b,c,0,0,0)

#define TOK 36864
#define SEQ 9216
#define CH 128
#define WL 2304
#define ATTN_SCALE (1.0f/1179648.0f)

__device__ __forceinline__ float b2f(unsigned short u){
  union{unsigned i; float f;} c; c.i = ((unsigned)u)<<16; return c.f;
}
__device__ __forceinline__ unsigned short f2b(float f){
  union{float f; unsigned i;} c; c.f = f;
  unsigned r = c.i + 0x7fffu + ((c.i>>16)&1u);
  return (unsigned short)(r>>16);
}

// ---------------- K0: weight transpose f32->bf16 + param pack ----------------
__global__ __launch_bounds__(256) void k_prep(const float* __restrict__ wgq,
    const float* __restrict__ wkv, const float* __restrict__ wo1, const float* __restrict__ wo2,
    const float* __restrict__ bgq, const float* __restrict__ bkv, const float* __restrict__ bo1,
    const float* __restrict__ lng, const float* __restrict__ lnb,
    unsigned short* __restrict__ Wt, unsigned short* __restrict__ Wt1,
    unsigned short* __restrict__ Wt2, unsigned short* __restrict__ P)
{
  int idx = blockIdx.x*256 + threadIdx.x;
  if (idx < 65536){
    int n = idx>>7, k = idx&127;
    Wt[idx] = f2b((n<256) ? wgq[k*256+n] : wkv[k*256+(n-256)]);
  } else if (idx < 81920){
    int t2 = idx-65536; int n = t2>>7, k = t2&127;
    Wt1[t2] = f2b(wo1[k*128+n]);
  } else if (idx < 98304){
    int t2 = idx-81920; int n = t2>>7, k = t2&127;
    Wt2[t2] = f2b(wo2[k*128+n]);
  } else if (idx < 99200){
    int j = idx-98304;
    float v;
    if (j<256)      v = bgq[j];
    else if (j<512) v = bkv[j-256];
    else if (j<640) v = bo1[j-512];
    else if (j<768) v = lng[j-640];
    else            v = lnb[j-768];
    P[j] = f2b(v);   // P: [bgq|bkv|bo1|lng|lnb]
  }
}

// ---------------- K1: fused LN + projection GEMM + silu + window scatter ----------------
// One block = 64 tokens x ALL 512 cols (2 chunks of 256). LN computed once.
__global__ __launch_bounds__(256) void k_proj(const float* __restrict__ src,
    const unsigned short* __restrict__ Wt, const unsigned short* __restrict__ P,
    float* __restrict__ gate, unsigned short* __restrict__ Qw,
    unsigned short* __restrict__ Kw, unsigned short* __restrict__ Vt)
{
  __shared__ __align__(16) short lS[64][136];
  const int tid = threadIdx.x;
  const int w = tid>>6, l = tid&63, l16 = l&15, quad = l>>4;
  const int m0 = blockIdx.x*64;

  { // LayerNorm of this block's 64 rows into LDS (4 threads per row)
    int row = tid>>2, lam = tid&3;
    const float* sp = src + (m0+row)*CH + lam*32;
    float v[32]; float s = 0.f, sq = 0.f;
#pragma unroll
    for (int j=0;j<32;j++){ v[j] = sp[j]; s += v[j]; sq += v[j]*v[j]; }
    s += __shfl_xor(s,1); sq += __shfl_xor(sq,1);
    s += __shfl_xor(s,2); sq += __shfl_xor(sq,2);
    float mean = s*(1.f/128.f);
    float rstd = rsqrtf(sq*(1.f/128.f) - mean*mean + 1e-5f);
#pragma unroll
    for (int j=0;j<32;j++){
      int c = lam*32 + j;
      lS[row][c] = (short)f2b((v[j]-mean)*rstd*b2f(P[640+c]) + b2f(P[768+c]));
    }
  }
  __syncthreads();

  s8v a[4];
#pragma unroll
  for (int kc=0;kc<4;kc++) a[kc] = *(const s8v*)&lS[w*16+l16][kc*32+quad*8];

  // window mapping per output row (C-layout rows = quad*4+r)
  int tokv[4], gidx[4], posv[4];
#pragma unroll
  for (int r=0;r<4;r++){
    int token = m0 + w*16 + quad*4 + r;
    int bi = token / SEQ; int t = token - bi*SEQ;
    int i = t / 96; int j = t - i*96;
    int p = i - 24; if (p<0) p += 96;
    int q = j - 24; if (q<0) q += 96;
    int ihh = (p>=48); int rr = p - ihh*48;
    int iww = (q>=48); int ss = q - iww*48;
    tokv[r] = token;
    gidx[r] = bi*4 + ihh*2 + iww;
    posv[r] = rr*48 + ss;
  }

#pragma unroll
  for (int chunk=0; chunk<2; chunk++){
    f4v acc[16];
#pragma unroll
    for (int nt=0;nt<16;nt++){
      f4v z = {0.f,0.f,0.f,0.f}; acc[nt] = z;
      const unsigned short* bp = Wt + (chunk*256 + nt*16 + l16)*CH + quad*8;
#pragma unroll
      for (int kc=0;kc<4;kc++)
        acc[nt] = MFMA16(a[kc], *(const s8v*)(bp + kc*32), acc[nt]);
    }
#pragma unroll
    for (int nt=0;nt<16;nt++){
      int col = chunk*256 + nt*16 + l16;
      float bias = b2f(P[col]);     // P[0:512) = [bgq|bkv]
#pragma unroll
      for (int r=0;r<4;r++){
        float z = acc[nt][r] + bias;
        z = z / (1.0f + __expf(-z));            // silu
        if (col < 128){
          gate[tokv[r]*CH + col] = z;           // f32, parked in d_out
        } else if (col < 256){
          Qw[(gidx[r]*WL + posv[r])*CH + (col-128)] = f2b(z);
        } else if (col < 384){
          Kw[(gidx[r]*WL + posv[r])*CH + (col-256)] = f2b(z);
        } else {
          Vt[gidx[r]*CH*WL + (col-384)*WL + posv[r]] = f2b(z);  // V^T: [win][ch][pos]
        }
      }
    }
  }
}

// ---------------- K2: windowed attention, BM=128 (single-pass, analytic mask) ----------------
// attn aliases Qw: each block reads exactly the Q rows it later writes (no __restrict__).
__global__ __launch_bounds__(256) void k_attn(const unsigned short* Qw,
    const unsigned short* __restrict__ Kw, const unsigned short* __restrict__ Vt,
    unsigned short* attn)
{
  __shared__ __align__(16) short lK[64][136];   // K tile [key][ch]
  __shared__ __align__(16) short lV[128][72];   // V tile [ch][key]
  __shared__ __align__(16) short lP[4][32][72]; // per-wave P [row(2 halves)][key]
  const int tid = threadIdx.x;
  const int w = tid>>6, l = tid&63, l16 = l&15, quad = l>>4;
  const int g = blockIdx.y;
  const int q0 = blockIdx.x*128;
  const int ih = (g>>1)&1, iw = g&1;

  s8v aQ[2][4];
  int qrl[2][4], qcl[2][4];
#pragma unroll
  for (int h=0;h<2;h++){
    const unsigned short* qp = Qw + (g*WL + q0 + h*64 + w*16 + l16)*CH + quad*8;
#pragma unroll
    for (int kc=0;kc<4;kc++) aQ[h][kc] = *(const s8v*)(qp + kc*32);
#pragma unroll
    for (int r=0;r<4;r++){
      int qpj = q0 + h*64 + w*16 + quad*4 + r;
      int qr = qpj/48, qs = qpj - qr*48;
      qrl[h][r] = (qr>=24); qcl[h][r] = (qs>=24);
    }
  }

  f4v O[2][8];
#pragma unroll
  for (int h=0;h<2;h++)
#pragma unroll
    for (int i=0;i<8;i++){ f4v z = {0.f,0.f,0.f,0.f}; O[h][i] = z; }
  float lsum[2][4] = {{0.f,0.f,0.f,0.f},{0.f,0.f,0.f,0.f}};

  for (int k0=0; k0<WL; k0+=64){
    __syncthreads();
    {
      const unsigned short* Kg = Kw + (g*WL + k0)*CH;
#pragma unroll
      for (int it=0;it<4;it++){
        int li = tid + it*256;
        int row = li>>4, ch = (li&15)*8;
        *(s8v*)&lK[row][ch] = *(const s8v*)(Kg + row*CH + ch);
      }
      const unsigned short* Vg = Vt + g*CH*WL + k0;
#pragma unroll
      for (int it=0;it<4;it++){
        int idx = tid + it*256;
        int ch = idx>>3, pb = (idx&7)*8;
        *(s8v*)&lV[ch][pb] = *(const s8v*)(Vg + ch*WL + pb);
      }
    }
    __syncthreads();

#pragma unroll
    for (int h=0;h<2;h++){
      f4v S[4];
#pragma unroll
      for (int nt=0;nt<4;nt++){
        f4v z = {0.f,0.f,0.f,0.f}; S[nt] = z;
#pragma unroll
        for (int kc=0;kc<4;kc++)
          S[nt] = MFMA16(aQ[h][kc], *(const s8v*)&lK[nt*16+l16][kc*32+quad*8], S[nt]);
      }

#pragma unroll
      for (int nt=0;nt<4;nt++){
        int key = k0 + nt*16 + l16;
        int kr = key/48, ks = key - kr*48;
        int krl = (kr>=24), kcl = (ks>=24);
#pragma unroll
        for (int r=0;r<4;r++){
          bool masked = (ih && (krl != qrl[h][r])) || (iw && (kcl != qcl[h][r]));
          float p = masked ? 0.0f : __expf(S[nt][r]*ATTN_SCALE);
          unsigned short pb = f2b(p);
          lsum[h][r] += b2f(pb);
          lP[w][h*16 + quad*4 + r][nt*16+l16] = (short)pb;
        }
      }
      // P is wave-private: drain LDS writes, no block barrier needed
      asm volatile("s_waitcnt lgkmcnt(0)" ::: "memory");

#pragma unroll
      for (int kc2=0;kc2<2;kc2++){
        s8v aP = *(const s8v*)&lP[w][h*16 + l16][kc2*32+quad*8];
#pragma unroll
        for (int nt=0;nt<8;nt++)
          O[h][nt] = MFMA16(aP, *(const s8v*)&lV[nt*16+l16][kc2*32+quad*8], O[h][nt]);
      }
    }
  }

#pragma unroll
  for (int h=0;h<2;h++){
#pragma unroll
    for (int r=0;r<4;r++){
#pragma unroll
      for (int m=1;m<16;m<<=1) lsum[h][r] += __shfl_xor(lsum[h][r], m);
    }
    unsigned short* outp = attn + (g*WL + q0 + h*64 + w*16)*CH;
#pragma unroll
    for (int nt=0;nt<8;nt++){
#pragma unroll
      for (int r=0;r<4;r++)
        outp[(quad*4+r)*CH + nt*16 + l16] = f2b(O[h][nt][r] / lsum[h][r]);
    }
  }
}

// ---------------- K3: unwindow + gate + o1(silu) + o2 + residual (f32 out) ----------------
__global__ __launch_bounds__(256) void k_out(const unsigned short* __restrict__ attn,
    const unsigned short* __restrict__ Wo1, const unsigned short* __restrict__ P,
    const unsigned short* __restrict__ Wo2, const float* __restrict__ src,
    float* out)
{
  __shared__ __align__(16) short lA[64][136];
  __shared__ __align__(16) short lU[4][16][136];
  const int tid = threadIdx.x;
  const int w = tid>>6, l = tid&63, l16 = l&15, quad = l>>4;
  const int m0 = blockIdx.x*64;
  {
    int r_loc = tid>>2;
    int cb = (tid&3)*32;
    int token = m0 + r_loc;
    int bi = token / SEQ; int t = token - bi*SEQ;
    int i = t / 96; int j = t - i*96;
    int p = i - 24; if (p<0) p += 96;
    int q = j - 24; if (q<0) q += 96;
    int ihh = (p>=48); int rr = p - ihh*48;
    int iww = (q>=48); int ss = q - iww*48;
    int wb = (bi*4 + ihh*2 + iww)*WL + rr*48 + ss;
    const unsigned short* av = attn + wb*CH + cb;
    const float* gv = out + token*CH + cb;    // gate parked in out[0:TOK*CH)
#pragma unroll
    for (int u=0;u<4;u++){
      s8v a8 = *(const s8v*)(av + u*8);
      float4 g0 = *(const float4*)(gv + u*8);
      float4 g1 = *(const float4*)(gv + u*8 + 4);
      s8v o;
      o[0]=(short)f2b(b2f((unsigned short)a8[0])*g0.x);
      o[1]=(short)f2b(b2f((unsigned short)a8[1])*g0.y);
      o[2]=(short)f2b(b2f((unsigned short)a8[2])*g0.z);
      o[3]=(short)f2b(b2f((unsigned short)a8[3])*g0.w);
      o[4]=(short)f2b(b2f((unsigned short)a8[4])*g1.x);
      o[5]=(short)f2b(b2f((unsigned short)a8[5])*g1.y);
      o[6]=(short)f2b(b2f((unsigned short)a8[6])*g1.z);
      o[7]=(short)f2b(b2f((unsigned short)a8[7])*g1.w);
      *(s8v*)&lA[r_loc][cb + u*8] = o;
    }
  }
  __syncthreads();

  s8v aA[4];
#pragma unroll
  for (int kc=0;kc<4;kc++) aA[kc] = *(const s8v*)&lA[w*16+l16][kc*32+quad*8];
  f4v acc[8];
#pragma unroll
  for (int nt=0;nt<8;nt++){
    f4v z = {0.f,0.f,0.f,0.f}; acc[nt] = z;
    const unsigned short* bp = Wo1 + (nt*16+l16)*CH + quad*8;
#pragma unroll
    for (int kc=0;kc<4;kc++) acc[nt] = MFMA16(aA[kc], *(const s8v*)(bp + kc*32), acc[nt]);
  }
#pragma unroll
  for (int nt=0;nt<8;nt++){
    int col = nt*16 + l16;
    float bias = b2f(P[512+col]);   // bo1
#pragma unroll
    for (int r=0;r<4;r++){
      float z = acc[nt][r] + bias;
      z = z / (1.0f + __expf(-z));
      lU[w][quad*4+r][col] = (short)f2b(z);
    }
  }
  __syncthreads();

  s8v aU[4];
#pragma unroll
  for (int kc=0;kc<4;kc++) aU[kc] = *(const s8v*)&lU[w][l16][kc*32+quad*8];
  f4v acc2[8];
#pragma unroll
  for (int nt=0;nt<8;nt++){
    f4v z = {0.f,0.f,0.f,0.f}; acc2[nt] = z;
    const unsigned short* bp = Wo2 + (nt*16+l16)*CH + quad*8;
#pragma unroll
    for (int kc=0;kc<4;kc++) acc2[nt] = MFMA16(aU[kc], *(const s8v*)(bp + kc*32), acc2[nt]);
  }
#pragma unroll
  for (int nt=0;nt<8;nt++){
#pragma unroll
    for (int r=0;r<4;r++){
      int token = m0 + w*16 + quad*4 + r;
      int col = nt*16 + l16;
      float y = acc2[nt][r] + src[token*CH + col];
      out[token*CH + col] = y;
      out[TOK*CH + token*CH + col] = y;
    }
  }
}

extern "C" void kernel_launch(void* const* d_in, const int* in_sizes, int n_in,
                              void* d_out, int out_size, void* d_ws, size_t ws_size,
                              hipStream_t stream)
{
  const float* src = (const float*)d_in[0];
  // d_in[1]=target(==source), d_in[2]=mask (analytic), d_in[3]=h, d_in[4]=w
  const float* lng = (const float*)d_in[5];
  const float* lnb = (const float*)d_in[6];
  const float* wgq = (const float*)d_in[7];
  const float* bgq = (const float*)d_in[8];
  const float* wkv = (const float*)d_in[9];
  const float* bkv = (const float*)d_in[10];
  const float* wo1 = (const float*)d_in[11];
  const float* bo1 = (const float*)d_in[12];
  const float* wo2 = (const float*)d_in[13];

  // Workspace 27.2 MiB: P | Wt | Wt1 | Wt2 | Qw(attn overlays) | Kw | Vt
  char* ws = (char*)d_ws;
  unsigned short* P   = (unsigned short*)(ws);             // 896 bf16 params
  unsigned short* Wt  = (unsigned short*)(ws + 2048);      // 512x128 W^T
  unsigned short* Wt1 = (unsigned short*)(ws + 133120);    // 128x128
  unsigned short* Wt2 = (unsigned short*)(ws + 165888);    // 128x128
  unsigned short* Qw  = (unsigned short*)(ws + 198656);    // 16x2304x128
  unsigned short* Kw  = (unsigned short*)(ws + 9635840);   // 16x2304x128
  unsigned short* Vt  = (unsigned short*)(ws + 19073024);  // 16x128x2304 (V^T)
  float* out = (float*)d_out;                              // f32; gate in out[0:TOK*CH)

  k_prep<<<dim3(388),   dim3(256), 0, stream>>>(wgq, wkv, wo1, wo2, bgq, bkv, bo1, lng, lnb,
                                                Wt, Wt1, Wt2, P);
  k_proj<<<dim3(576),   dim3(256), 0, stream>>>(src, Wt, P, out, Qw, Kw, Vt);
  k_attn<<<dim3(18,16), dim3(256), 0, stream>>>(Qw, Kw, Vt, Qw);
  k_out <<<dim3(576),   dim3(256), 0, stream>>>(Qw, Wt1, P, Wt2, src, out);
}

// Round 8
// 395.535 us; speedup vs baseline: 1.1487x; 1.1487x over previous
//
#include <hip/hip_runtime.h>

typedef short s8v __attribute__((ext_vector_type(8)));
typedef float f4v __attribute__((ext_vector_type(4)));

#define MFMA16(a,b,c) __builtin_amdgcn_mfma_f32_16x16x32_bf16(a,b,c,0,0,0)

#define TOK 36864
#define SEQ 9216
#define CH 128
#define WL 2304
#define ATTN_SCALE (1.0f/1179648.0f)

__device__ __forceinline__ float b2f(unsigned short u){
  union{unsigned i; float f;} c; c.i = ((unsigned)u)<<16; return c.f;
}
__device__ __forceinline__ unsigned short f2b(float f){
  union{float f; unsigned i;} c; c.f = f;
  unsigned r = c.i + 0x7fffu + ((c.i>>16)&1u);
  return (unsigned short)(r>>16);
}
// window (g,pos) -> token (inverse of the roll+split map)
__device__ __forceinline__ int wtok(int g, int pos){
  int bi = g>>2, ih = (g>>1)&1, iw = g&1;
  int rr = pos/48, ss = pos - rr*48;
  int p = ih*48 + rr, q = iw*48 + ss;
  int i = p + 24; if (i >= 96) i -= 96;
  int j = q + 24; if (j >= 96) j -= 96;
  return bi*SEQ + i*96 + j;
}

// ---------------- K0: weight transpose f32->bf16 + param pack ----------------
__global__ __launch_bounds__(256) void k_prep(const float* __restrict__ wgq,
    const float* __restrict__ wkv, const float* __restrict__ wo1, const float* __restrict__ wo2,
    const float* __restrict__ bgq, const float* __restrict__ bkv, const float* __restrict__ bo1,
    const float* __restrict__ lng, const float* __restrict__ lnb,
    unsigned short* __restrict__ Wt, unsigned short* __restrict__ Wt1,
    unsigned short* __restrict__ Wt2, unsigned short* __restrict__ P)
{
  int idx = blockIdx.x*256 + threadIdx.x;
  if (idx < 65536){
    int n = idx>>7, k = idx&127;
    Wt[idx] = f2b((n<256) ? wgq[k*256+n] : wkv[k*256+(n-256)]);
  } else if (idx < 81920){
    int t2 = idx-65536; int n = t2>>7, k = t2&127;
    Wt1[t2] = f2b(wo1[k*128+n]);
  } else if (idx < 98304){
    int t2 = idx-81920; int n = t2>>7, k = t2&127;
    Wt2[t2] = f2b(wo2[k*128+n]);
  } else if (idx < 99200){
    int j = idx-98304;
    float v;
    if (j<256)      v = bgq[j];
    else if (j<512) v = bkv[j-256];
    else if (j<640) v = bo1[j-512];
    else if (j<768) v = lng[j-640];
    else            v = lnb[j-768];
    P[j] = f2b(v);   // P: [bgq|bkv|bo1|lng|lnb]
  }
}

// ---------------- K1: fused LN + projection GEMM + silu ----------------
// One block = 64 tokens x ALL 512 cols. V now written TOKEN-layout (coalesced);
// window scatter for Q/K only (4x32B txn/instr — proven unamplified).
__global__ __launch_bounds__(256) void k_proj(const float* __restrict__ src,
    const unsigned short* __restrict__ Wt, const unsigned short* __restrict__ P,
    float* __restrict__ gate, unsigned short* __restrict__ Qw,
    unsigned short* __restrict__ Kw, unsigned short* __restrict__ Vb)
{
  __shared__ __align__(16) short lS[64][136];
  const int tid = threadIdx.x;
  const int w = tid>>6, l = tid&63, l16 = l&15, quad = l>>4;
  const int m0 = blockIdx.x*64;

  { // LayerNorm of 64 rows into LDS (4 threads per row)
    int row = tid>>2, lam = tid&3;
    const float* sp = src + (m0+row)*CH + lam*32;
    float v[32]; float s = 0.f, sq = 0.f;
#pragma unroll
    for (int j=0;j<32;j++){ v[j] = sp[j]; s += v[j]; sq += v[j]*v[j]; }
    s += __shfl_xor(s,1); sq += __shfl_xor(sq,1);
    s += __shfl_xor(s,2); sq += __shfl_xor(sq,2);
    float mean = s*(1.f/128.f);
    float rstd = rsqrtf(sq*(1.f/128.f) - mean*mean + 1e-5f);
#pragma unroll
    for (int j=0;j<32;j++){
      int c = lam*32 + j;
      lS[row][c] = (short)f2b((v[j]-mean)*rstd*b2f(P[640+c]) + b2f(P[768+c]));
    }
  }
  __syncthreads();

  s8v a[4];
#pragma unroll
  for (int kc=0;kc<4;kc++) a[kc] = *(const s8v*)&lS[w*16+l16][kc*32+quad*8];

  int tokv[4], gidx[4], posv[4];
#pragma unroll
  for (int r=0;r<4;r++){
    int token = m0 + w*16 + quad*4 + r;
    int bi = token / SEQ; int t = token - bi*SEQ;
    int i = t / 96; int j = t - i*96;
    int p = i - 24; if (p<0) p += 96;
    int q = j - 24; if (q<0) q += 96;
    int ihh = (p>=48); int rr = p - ihh*48;
    int iww = (q>=48); int ss = q - iww*48;
    tokv[r] = token;
    gidx[r] = bi*4 + ihh*2 + iww;
    posv[r] = rr*48 + ss;
  }

#pragma unroll
  for (int chunk=0; chunk<2; chunk++){
    f4v acc[16];
#pragma unroll
    for (int nt=0;nt<16;nt++){
      f4v z = {0.f,0.f,0.f,0.f}; acc[nt] = z;
      const unsigned short* bp = Wt + (chunk*256 + nt*16 + l16)*CH + quad*8;
#pragma unroll
      for (int kc=0;kc<4;kc++)
        acc[nt] = MFMA16(a[kc], *(const s8v*)(bp + kc*32), acc[nt]);
    }
#pragma unroll
    for (int nt=0;nt<16;nt++){
      int col = chunk*256 + nt*16 + l16;
      float bias = b2f(P[col]);
#pragma unroll
      for (int r=0;r<4;r++){
        float z = acc[nt][r] + bias;
        z = z / (1.0f + __expf(-z));            // silu
        if (col < 128){
          gate[tokv[r]*CH + col] = z;           // f32, parked in d_out
        } else if (col < 256){
          Qw[(gidx[r]*WL + posv[r])*CH + (col-128)] = f2b(z);
        } else if (col < 384){
          Kw[(gidx[r]*WL + posv[r])*CH + (col-256)] = f2b(z);
        } else {
          Vb[tokv[r]*CH + (col-384)] = f2b(z);  // token-layout (k_vt transposes)
        }
      }
    }
  }
}

// ---------------- K1b: V token-layout -> windowed V^T [g][ch][pos] ----------------
// Conflict-free LDS transpose (pitch 66 shorts): stage bank=lane, read bank=33*key≡key.
__global__ __launch_bounds__(256) void k_vt(const unsigned short* __restrict__ Vb,
    unsigned short* __restrict__ Vt)
{
  __shared__ short lR[64*66];
  const int tid = threadIdx.x;
  const int g = blockIdx.y;
  const int q0 = blockIdx.x*64;
  const int lane = tid&63, grp = tid>>6;
#pragma unroll 4
  for (int p=0;p<16;p++){
    int key = p*4 + grp;
    int token = wtok(g, q0+key);
    unsigned v = *(const unsigned*)(Vb + token*CH + lane*2);   // 2 ch per lane
    *(unsigned*)&lR[key*66 + lane*2] = v;
  }
  __syncthreads();
#pragma unroll 8
  for (int i=0;i<32;i++){
    int ch = grp*32 + i;
    Vt[g*CH*WL + ch*WL + q0 + lane] = (unsigned short)lR[lane*66 + ch];
  }
}

// ---------------- K2: windowed attention, BM=64 (r6 structure) ----------------
// attn aliases Qw: each block reads exactly the Q rows it later writes (no __restrict__).
__global__ __launch_bounds__(256) void k_attn(const unsigned short* Qw,
    const unsigned short* __restrict__ Kw, const unsigned short* __restrict__ Vt,
    unsigned short* attn)
{
  __shared__ __align__(16) short lK[64][136];   // K tile [key][ch]
  __shared__ __align__(16) short lV[128][72];   // V tile [ch][key]
  __shared__ __align__(16) short lP[4][16][72]; // per-wave P [row][key]
  const int tid = threadIdx.x;
  const int w = tid>>6, l = tid&63, l16 = l&15, quad = l>>4;
  const int g = blockIdx.y;
  const int q0 = blockIdx.x*64;
  const int ih = (g>>1)&1, iw = g&1;

  const unsigned short* qp = Qw + (g*WL + q0 + w*16 + l16)*CH + quad*8;
  s8v aQ[4];
#pragma unroll
  for (int kc=0;kc<4;kc++) aQ[kc] = *(const s8v*)(qp + kc*32);

  int qrl[4], qcl[4];
#pragma unroll
  for (int r=0;r<4;r++){
    int qpj = q0 + w*16 + quad*4 + r;
    int qr = qpj/48, qs = qpj - qr*48;
    qrl[r] = (qr>=24); qcl[r] = (qs>=24);
  }

  f4v O[8];
#pragma unroll
  for (int i=0;i<8;i++){ f4v z = {0.f,0.f,0.f,0.f}; O[i] = z; }
  float lsum[4] = {0.f,0.f,0.f,0.f};

  for (int k0=0; k0<WL; k0+=64){
    __syncthreads();
    {
      const unsigned short* Kg = Kw + (g*WL + k0)*CH;
#pragma unroll
      for (int it=0;it<4;it++){
        int li = tid + it*256;
        int row = li>>4, ch = (li&15)*8;
        *(s8v*)&lK[row][ch] = *(const s8v*)(Kg + row*CH + ch);
      }
      const unsigned short* Vg = Vt + g*CH*WL + k0;
#pragma unroll
      for (int it=0;it<4;it++){
        int idx = tid + it*256;
        int ch = idx>>3, pb = (idx&7)*8;
        *(s8v*)&lV[ch][pb] = *(const s8v*)(Vg + ch*WL + pb);
      }
    }
    __syncthreads();

    f4v S[4];
#pragma unroll
    for (int nt=0;nt<4;nt++){
      f4v z = {0.f,0.f,0.f,0.f}; S[nt] = z;
#pragma unroll
      for (int kc=0;kc<4;kc++)
        S[nt] = MFMA16(aQ[kc], *(const s8v*)&lK[nt*16+l16][kc*32+quad*8], S[nt]);
    }

#pragma unroll
    for (int nt=0;nt<4;nt++){
      int key = k0 + nt*16 + l16;
      int kr = key/48, ks = key - kr*48;
      int krl = (kr>=24), kcl = (ks>=24);
#pragma unroll
      for (int r=0;r<4;r++){
        bool masked = (ih && (krl != qrl[r])) || (iw && (kcl != qcl[r]));
        float p = masked ? 0.0f : __expf(S[nt][r]*ATTN_SCALE);
        unsigned short pb = f2b(p);
        lsum[r] += b2f(pb);
        lP[w][quad*4+r][nt*16+l16] = (short)pb;
      }
    }
    // P is wave-private (validated r7): drain LDS, no block barrier
    asm volatile("s_waitcnt lgkmcnt(0)" ::: "memory");

#pragma unroll
    for (int kc2=0;kc2<2;kc2++){
      s8v aP = *(const s8v*)&lP[w][l16][kc2*32+quad*8];
#pragma unroll
      for (int nt=0;nt<8;nt++)
        O[nt] = MFMA16(aP, *(const s8v*)&lV[nt*16+l16][kc2*32+quad*8], O[nt]);
    }
  }

#pragma unroll
  for (int r=0;r<4;r++){
#pragma unroll
    for (int m=1;m<16;m<<=1) lsum[r] += __shfl_xor(lsum[r], m);
  }
  unsigned short* outp = attn + (g*WL + q0 + w*16)*CH;
#pragma unroll
  for (int nt=0;nt<8;nt++){
#pragma unroll
    for (int r=0;r<4;r++)
      outp[(quad*4+r)*CH + nt*16 + l16] = f2b(O[nt][r] / lsum[r]);
  }
}

// ---------------- K3: unwindow + gate + o1(silu) + o2 + residual (f32 out) ----------------
__global__ __launch_bounds__(256) void k_out(const unsigned short* __restrict__ attn,
    const unsigned short* __restrict__ Wo1, const unsigned short* __restrict__ P,
    const unsigned short* __restrict__ Wo2, const float* __restrict__ src,
    float* out)
{
  __shared__ __align__(16) short lA[64][136];
  __shared__ __align__(16) short lU[4][16][136];
  const int tid = threadIdx.x;
  const int w = tid>>6, l = tid&63, l16 = l&15, quad = l>>4;
  const int m0 = blockIdx.x*64;
  {
    int r_loc = tid>>2;
    int cb = (tid&3)*32;
    int token = m0 + r_loc;
    int bi = token / SEQ; int t = token - bi*SEQ;
    int i = t / 96; int j = t - i*96;
    int p = i - 24; if (p<0) p += 96;
    int q = j - 24; if (q<0) q += 96;
    int ihh = (p>=48); int rr = p - ihh*48;
    int iww = (q>=48); int ss = q - iww*48;
    int wb = (bi*4 + ihh*2 + iww)*WL + rr*48 + ss;
    const unsigned short* av = attn + wb*CH + cb;
    const float* gv = out + token*CH + cb;    // gate parked in out[0:TOK*CH)
#pragma unroll
    for (int u=0;u<4;u++){
      s8v a8 = *(const s8v*)(av + u*8);
      float4 g0 = *(const float4*)(gv + u*8);
      float4 g1 = *(const float4*)(gv + u*8 + 4);
      s8v o;
      o[0]=(short)f2b(b2f((unsigned short)a8[0])*g0.x);
      o[1]=(short)f2b(b2f((unsigned short)a8[1])*g0.y);
      o[2]=(short)f2b(b2f((unsigned short)a8[2])*g0.z);
      o[3]=(short)f2b(b2f((unsigned short)a8[3])*g0.w);
      o[4]=(short)f2b(b2f((unsigned short)a8[4])*g1.x);
      o[5]=(short)f2b(b2f((unsigned short)a8[5])*g1.y);
      o[6]=(short)f2b(b2f((unsigned short)a8[6])*g1.z);
      o[7]=(short)f2b(b2f((unsigned short)a8[7])*g1.w);
      *(s8v*)&lA[r_loc][cb + u*8] = o;
    }
  }
  __syncthreads();

  s8v aA[4];
#pragma unroll
  for (int kc=0;kc<4;kc++) aA[kc] = *(const s8v*)&lA[w*16+l16][kc*32+quad*8];
  f4v acc[8];
#pragma unroll
  for (int nt=0;nt<8;nt++){
    f4v z = {0.f,0.f,0.f,0.f}; acc[nt] = z;
    const unsigned short* bp = Wo1 + (nt*16+l16)*CH + quad*8;
#pragma unroll
    for (int kc=0;kc<4;kc++) acc[nt] = MFMA16(aA[kc], *(const s8v*)(bp + kc*32), acc[nt]);
  }
#pragma unroll
  for (int nt=0;nt<8;nt++){
    int col = nt*16 + l16;
    float bias = b2f(P[512+col]);   // bo1
#pragma unroll
    for (int r=0;r<4;r++){
      float z = acc[nt][r] + bias;
      z = z / (1.0f + __expf(-z));
      lU[w][quad*4+r][col] = (short)f2b(z);
    }
  }
  __syncthreads();

  s8v aU[4];
#pragma unroll
  for (int kc=0;kc<4;kc++) aU[kc] = *(const s8v*)&lU[w][l16][kc*32+quad*8];
  f4v acc2[8];
#pragma unroll
  for (int nt=0;nt<8;nt++){
    f4v z = {0.f,0.f,0.f,0.f}; acc2[nt] = z;
    const unsigned short* bp = Wo2 + (nt*16+l16)*CH + quad*8;
#pragma unroll
    for (int kc=0;kc<4;kc++) acc2[nt] = MFMA16(aU[kc], *(const s8v*)(bp + kc*32), acc2[nt]);
  }
#pragma unroll
  for (int nt=0;nt<8;nt++){
#pragma unroll
    for (int r=0;r<4;r++){
      int token = m0 + w*16 + quad*4 + r;
      int col = nt*16 + l16;
      float y = acc2[nt][r] + src[token*CH + col];
      out[token*CH + col] = y;
      out[TOK*CH + token*CH + col] = y;
    }
  }
}

extern "C" void kernel_launch(void* const* d_in, const int* in_sizes, int n_in,
                              void* d_out, int out_size, void* d_ws, size_t ws_size,
                              hipStream_t stream)
{
  const float* src = (const float*)d_in[0];
  const float* lng = (const float*)d_in[5];
  const float* lnb = (const float*)d_in[6];
  const float* wgq = (const float*)d_in[7];
  const float* bgq = (const float*)d_in[8];
  const float* wkv = (const float*)d_in[9];
  const float* bkv = (const float*)d_in[10];
  const float* wo1 = (const float*)d_in[11];
  const float* bo1 = (const float*)d_in[12];
  const float* wo2 = (const float*)d_in[13];

  // Workspace 36.2 MiB: P | Wt | Wt1 | Wt2 | Qw(attn overlays) | Kw | Vt | Vb
  char* ws = (char*)d_ws;
  unsigned short* P   = (unsigned short*)(ws);
  unsigned short* Wt  = (unsigned short*)(ws + 2048);
  unsigned short* Wt1 = (unsigned short*)(ws + 133120);
  unsigned short* Wt2 = (unsigned short*)(ws + 165888);
  unsigned short* Qw  = (unsigned short*)(ws + 198656);    // window layout
  unsigned short* Kw  = (unsigned short*)(ws + 9635840);   // window layout
  unsigned short* Vt  = (unsigned short*)(ws + 19073024);  // [g][ch][pos]
  unsigned short* Vb  = (unsigned short*)(ws + 28510208);  // token layout
  float* out = (float*)d_out;                              // gate in out[0:TOK*CH)

  k_prep<<<dim3(388),   dim3(256), 0, stream>>>(wgq, wkv, wo1, wo2, bgq, bkv, bo1, lng, lnb,
                                                Wt, Wt1, Wt2, P);
  k_proj<<<dim3(576),   dim3(256), 0, stream>>>(src, Wt, P, out, Qw, Kw, Vb);
  k_vt  <<<dim3(36,16), dim3(256), 0, stream>>>(Vb, Vt);
  k_attn<<<dim3(36,16), dim3(256), 0, stream>>>(Qw, Kw, Vt, Qw);
  k_out <<<dim3(576),   dim3(256), 0, stream>>>(Qw, Wt1, P, Wt2, src, out);
}